// Round 1
// baseline (331.658 us; speedup 1.0000x reference)
//
#include <hip/hip_runtime.h>
#include <math.h>

#define NQ     12
#define DIM    4096      // 2^12 amplitudes
#define NPASS  36        // 6 enc + 24 layer + 6 final, each a 2-wire (4x4) pass

__device__ __forceinline__ float2 cmul(float2 a, float2 b) {
    return make_float2(fmaf(a.x, b.x, -(a.y * b.y)), fmaf(a.x, b.y, a.y * b.x));
}

// U = RY(2*h)  (h = half-angle), as complex 2x2 row-major
__device__ __forceinline__ void ry_u(float h, float2 U[4]) {
    float c, s;
    sincosf(h, &s, &c);
    U[0] = make_float2(c, 0.f);  U[1] = make_float2(-s, 0.f);
    U[2] = make_float2(s, 0.f);  U[3] = make_float2(c, 0.f);
}

// Fused per-layer per-wire unitary U = Rz(az)*Ry(ay)*Rx(ax), angles = w*scale
__device__ __forceinline__ void fused_u(const float* __restrict__ w, float sc,
                                        int l, int q, float2 U[4]) {
    const float hx = 0.5f * sc * w[l * 36 + q];
    const float hy = 0.5f * sc * w[l * 36 + 12 + q];
    const float hz = 0.5f * sc * w[l * 36 + 24 + q];
    float cx, sx, cy, sy, cz, sz;
    sincosf(hx, &sx, &cx);
    sincosf(hy, &sy, &cy);
    sincosf(hz, &sz, &cz);
    // T = Ry*Rx
    const float2 T00 = make_float2(cy * cx,  sy * sx);
    const float2 T01 = make_float2(-sy * cx, -cy * sx);
    const float2 T10 = make_float2(sy * cx,  -cy * sx);
    const float2 T11 = make_float2(cy * cx,  -sy * sx);
    const float2 e0 = make_float2(cz, -sz);   // e^{-i az/2}
    const float2 e1 = make_float2(cz,  sz);   // e^{+i az/2}
    U[0] = cmul(e0, T00); U[1] = cmul(e0, T01);
    U[2] = cmul(e1, T10); U[3] = cmul(e1, T11);
}

extern "C" __global__ void __launch_bounds__(256)
qsim_kernel(const float* __restrict__ x, const float* __restrict__ Wp,
            const float* __restrict__ bp, const float* __restrict__ w,
            const float* __restrict__ scal, float* __restrict__ out)
{
    __shared__ __align__(16) float sRe[DIM];
    __shared__ __align__(16) float sIm[DIM];
    __shared__ float2 sM[NPASS][16];   // 4x4 complex matrix per pass
    __shared__ float  sXq[NQ];
    __shared__ float  sWred[4][NQ];

    const int t = threadIdx.x;
    const int b = blockIdx.x;

    // ---- zero state (thread 0 also owns sRe[0], so set |0...0> right after) ----
    const float4 z4 = make_float4(0.f, 0.f, 0.f, 0.f);
    #pragma unroll
    for (int k = 0; k < 4; ++k) {
        ((float4*)sRe)[t + (k << 8)] = z4;
        ((float4*)sIm)[t + (k << 8)] = z4;
    }
    if (t == 0) sRe[0] = 1.f;

    // ---- projection: xq[q] = tanh(x.W[q] + b[q]) * pi ; t = 16*q + h ----
    {
        const int q = t >> 4, h = t & 15;
        if (q < NQ) {
            const float* xr = x + (size_t)b * 256;
            const float* wr = Wp + q * 256;
            float acc = 0.f;
            #pragma unroll
            for (int m2 = 0; m2 < 16; ++m2) {
                const int f = h + (m2 << 4);
                acc = fmaf(xr[f], wr[f], acc);
            }
            acc += __shfl_xor(acc, 1);
            acc += __shfl_xor(acc, 2);
            acc += __shfl_xor(acc, 4);
            acc += __shfl_xor(acc, 8);
            if (h == 0) sXq[q] = tanhf(acc + bp[q]) * 3.14159265358979f;
        }
    }
    __syncthreads();

    // ---- build the 36 pass matrices (kron of two 2x2) ----
    if (t < NPASS) {
        const int g = t / 6, p = t % 6;
        const int qa = 2 * p, qb = 2 * p + 1;
        float2 A[4], B[4];
        if (g == 0) {                 // encoding RY (per-sample angles, normalized)
            float nrm = 1e-10f;
            #pragma unroll
            for (int k = 0; k < NQ; ++k) nrm += sXq[k] * sXq[k];
            const float inv = 3.14159265358979f * rsqrtf(nrm);  // enc = xq*inv
            ry_u(0.5f * sXq[qa] * inv, A);
            ry_u(0.5f * sXq[qb] * inv, B);
        } else if (g <= 4) {          // fused layer rotations
            const float sc = scal[g - 1];
            fused_u(w, sc, g - 1, qa, A);
            fused_u(w, sc, g - 1, qb, B);
        } else {                      // final RY layer (unscaled weights)
            ry_u(0.5f * w[144 + qa], A);
            ry_u(0.5f * w[144 + qb], B);
        }
        // M[j][jp] = A[j>>1][jp>>1] * B[j&1][jp&1]
        #pragma unroll
        for (int j = 0; j < 4; ++j)
            #pragma unroll
            for (int jp = 0; jp < 4; ++jp)
                sM[t][(j << 2) + jp] =
                    cmul(A[((j >> 1) << 1) + (jp >> 1)], B[((j & 1) << 1) + (jp & 1)]);
    }
    __syncthreads();

    // ---- 36 full-state passes; layout rotates by 2 bits per pass (rot12 = id) ----
    // Pass pp: active wires (2p,2p+1) sit at bit positions (11,10).
    // Read old position (j<<10)|tq, write new position 4*tq + j (contiguous).
    // CNOT chain (prefix-XOR perm, new[j]=old[j^(j>>1)]) fused into the gather of
    // the first pass after each layer (pp = 12,18,24,30; layout is standard there).
    for (int pp = 0; pp < NPASS; ++pp) {
        float2 M[16];
        #pragma unroll
        for (int e = 0; e < 16; ++e) M[e] = sM[pp][e];
        const bool chain = (pp >= 12) && ((pp % 6) == 0);

        float aR[4][4], aI[4][4];
        #pragma unroll
        for (int it = 0; it < 4; ++it) {
            const int tq = t + (it << 8);
            #pragma unroll
            for (int j = 0; j < 4; ++j) {
                int m = (j << 10) | tq;
                if (chain) m ^= (m >> 1);
                aR[it][j] = sRe[m];
                aI[it][j] = sIm[m];
            }
        }
        __syncthreads();   // all reads done before any in-place write

        #pragma unroll
        for (int it = 0; it < 4; ++it) {
            const int tq = t + (it << 8);
            float oR[4], oI[4];
            #pragma unroll
            for (int j = 0; j < 4; ++j) {
                float accR = 0.f, accI = 0.f;
                #pragma unroll
                for (int jp = 0; jp < 4; ++jp) {
                    const float2 mm = M[(j << 2) + jp];
                    const float ar = aR[it][jp], ai = aI[it][jp];
                    accR = fmaf(mm.x, ar, accR);
                    accR = fmaf(-mm.y, ai, accR);
                    accI = fmaf(mm.x, ai, accI);
                    accI = fmaf(mm.y, ar, accI);
                }
                oR[j] = accR; oI[j] = accI;
            }
            ((float4*)sRe)[tq] = make_float4(oR[0], oR[1], oR[2], oR[3]);
            ((float4*)sIm)[tq] = make_float4(oI[0], oI[1], oI[2], oI[3]);
        }
        __syncthreads();
    }

    // ---- measurement: <Z_q>; state is in standard layout (wire q = bit 11-q) ----
    // Thread t owns indices i = t + 256*k: bits 7..0 = t (wires 4..11),
    // bits 11..8 = k (wires 0..3).
    float zt = 0.f, z0 = 0.f, z1 = 0.f, z2 = 0.f, z3 = 0.f;
    #pragma unroll
    for (int k = 0; k < 16; ++k) {
        const int i = t + (k << 8);
        const float re = sRe[i], im = sIm[i];
        const float pv = fmaf(re, re, im * im);
        zt += pv;
        z0 += ((k >> 3) & 1) ? -pv : pv;   // wire 0 (bit 11)
        z1 += ((k >> 2) & 1) ? -pv : pv;   // wire 1
        z2 += ((k >> 1) & 1) ? -pv : pv;   // wire 2
        z3 += (k & 1)        ? -pv : pv;   // wire 3
    }
    float z[NQ];
    z[0] = z0; z[1] = z1; z[2] = z2; z[3] = z3;
    #pragma unroll
    for (int q = 4; q < NQ; ++q)
        z[q] = ((t >> (11 - q)) & 1) ? -zt : zt;

    #pragma unroll
    for (int q = 0; q < NQ; ++q) {
        float v = z[q];
        v += __shfl_xor(v, 1);  v += __shfl_xor(v, 2);
        v += __shfl_xor(v, 4);  v += __shfl_xor(v, 8);
        v += __shfl_xor(v, 16); v += __shfl_xor(v, 32);
        z[q] = v;
    }
    const int wv = t >> 6;
    if ((t & 63) == 0) {
        #pragma unroll
        for (int q = 0; q < NQ; ++q) sWred[wv][q] = z[q];
    }
    __syncthreads();
    if (t < NQ)
        out[(size_t)b * NQ + t] = sWred[0][t] + sWred[1][t] + sWred[2][t] + sWred[3][t];
}

extern "C" void kernel_launch(void* const* d_in, const int* in_sizes, int n_in,
                              void* d_out, int out_size, void* d_ws, size_t ws_size,
                              hipStream_t stream) {
    const float* x    = (const float*)d_in[0];
    const float* Wp   = (const float*)d_in[1];
    const float* bp   = (const float*)d_in[2];
    const float* w    = (const float*)d_in[3];
    const float* scal = (const float*)d_in[4];
    float* outp = (float*)d_out;
    hipLaunchKernelGGL(qsim_kernel, dim3(4096), dim3(256), 0, stream,
                       x, Wp, bp, w, scal, outp);
}

// Round 2
// 228.958 us; speedup vs baseline: 1.4486x; 1.4486x over previous
//
#include <hip/hip_runtime.h>
#include <math.h>

#define NQ   12
#define DIM  4096
#define PI_F 3.14159265358979f

typedef __attribute__((ext_vector_type(2))) float f2;
typedef __attribute__((ext_vector_type(4))) float f4;

// XOR swizzle for bank-balanced rot-4 passes (bijective on 12-bit indices)
__device__ __forceinline__ int physaddr(int a) { return a ^ (((a >> 6) & 7) << 2); }

// 2x2 complex gate on amp pair (A=bit0-half, B=bit1-half); each f2 packs two amplitudes.
// u = {r00,i00,r01,i01,r10,i10,r11,i11}
__device__ __forceinline__ void gpair(f2& Ar, f2& Ai, f2& Br, f2& Bi, const float* u) {
    f2 nAr = u[0]*Ar - u[1]*Ai + u[2]*Br - u[3]*Bi;
    f2 nAi = u[0]*Ai + u[1]*Ar + u[2]*Bi + u[3]*Br;
    f2 nBr = u[4]*Ar - u[5]*Ai + u[6]*Br - u[7]*Bi;
    f2 nBi = u[4]*Ai + u[5]*Ar + u[6]*Bi + u[7]*Br;
    Ar = nAr; Ai = nAi; Br = nBr; Bi = nBi;
}

// gate acting WITHIN each f2 (amp0 = .x, amp1 = .y) — only .xx/.yy broadcasts (op_sel)
__device__ __forceinline__ void gintra(f2& Ar, f2& Ai, const float* u) {
    f2 U0r = {u[0], u[4]}, U0i = {u[1], u[5]}, U1r = {u[2], u[6]}, U1i = {u[3], u[7]};
    f2 nAr = U0r*Ar.xx + U1r*Ar.yy - U0i*Ai.xx - U1i*Ai.yy;
    f2 nAi = U0r*Ai.xx + U1r*Ai.yy + U0i*Ar.xx + U1i*Ar.yy;
    Ar = nAr; Ai = nAi;
}

extern "C" __global__ void __launch_bounds__(256, 4)
qsim_kernel(const float* __restrict__ x, const float* __restrict__ Wp,
            const float* __restrict__ bp, const float* __restrict__ w,
            const float* __restrict__ scal, float* __restrict__ out)
{
    __shared__ __align__(16) float sRe[DIM];
    __shared__ __align__(16) float sIm[DIM];
    __shared__ f4    sU[5][NQ][2];   // per-sweep per-wire fused 2x2 complex
    __shared__ float sXq[NQ];
    __shared__ float sWred[4][NQ];

    const int t = threadIdx.x;
    const int b = blockIdx.x;

    // ---- zero state; |0..0> amplitude (phys(0)==0) ----
    const f4 z4 = {0.f, 0.f, 0.f, 0.f};
    #pragma unroll
    for (int k = 0; k < 4; ++k) {
        ((f4*)sRe)[t + (k << 8)] = z4;
        ((f4*)sIm)[t + (k << 8)] = z4;
    }
    if (t == 0) sRe[0] = 1.f;

    // ---- projection: xq[q] = tanh(x.W[q] + b[q]) * pi ----
    {
        const int q = t >> 4, h = t & 15;
        if (q < NQ) {
            const float* xr = x + (size_t)b * 256;
            const float* wr = Wp + q * 256;
            float acc = 0.f;
            #pragma unroll
            for (int m2 = 0; m2 < 16; ++m2) {
                const int f = h + (m2 << 4);
                acc = fmaf(xr[f], wr[f], acc);
            }
            acc += __shfl_xor(acc, 1);
            acc += __shfl_xor(acc, 2);
            acc += __shfl_xor(acc, 4);
            acc += __shfl_xor(acc, 8);
            if (h == 0) sXq[q] = tanhf(acc + bp[q]) * PI_F;
        }
    }
    __syncthreads();

    // ---- build 60 fused 2x2 unitaries: sweep 0 = Rz*Ry*Rx*Ry_enc (layer 0),
    //      sweeps 1..3 = Rz*Ry*Rx (layers 1..3), sweep 4 = final RY ----
    if (t < 60) {
        const int s_ = t / 12, q = t - s_ * 12;
        float U[8];
        if (s_ == 4) {
            float c, s; sincosf(0.5f * w[144 + q], &s, &c);
            U[0]=c; U[1]=0.f; U[2]=-s; U[3]=0.f; U[4]=s; U[5]=0.f; U[6]=c; U[7]=0.f;
        } else {
            const float sc = scal[s_];
            const float hx = 0.5f * sc * w[s_ * 36 + q];
            const float hy = 0.5f * sc * w[s_ * 36 + 12 + q];
            const float hz = 0.5f * sc * w[s_ * 36 + 24 + q];
            float cx, sx, cy, sy, cz, sz;
            sincosf(hx, &sx, &cx); sincosf(hy, &sy, &cy); sincosf(hz, &sz, &cz);
            // T = Ry*Rx
            const float T00r = cy*cx, T00i =  sy*sx;
            const float T01r = -sy*cx, T01i = -cy*sx;
            const float T10r =  sy*cx, T10i = -cy*sx;
            const float T11r =  cy*cx, T11i = -sy*sx;
            // U = Rz*T : row0 *= (cz,-sz), row1 *= (cz,+sz)
            U[0] = cz*T00r + sz*T00i;  U[1] = cz*T00i - sz*T00r;
            U[2] = cz*T01r + sz*T01i;  U[3] = cz*T01i - sz*T01r;
            U[4] = cz*T10r - sz*T10i;  U[5] = cz*T10i + sz*T10r;
            U[6] = cz*T11r - sz*T11i;  U[7] = cz*T11i + sz*T11r;
            if (s_ == 0) {             // right-multiply by encoding RY (applied first)
                float nrm = 1e-10f;
                #pragma unroll
                for (int k2 = 0; k2 < NQ; ++k2) nrm += sXq[k2] * sXq[k2];
                const float inv = PI_F * rsqrtf(nrm);
                float ce, se; sincosf(0.5f * sXq[q] * inv, &se, &ce);
                const float r00 = U[0]*ce + U[2]*se, i00 = U[1]*ce + U[3]*se;
                const float r01 = U[2]*ce - U[0]*se, i01 = U[3]*ce - U[1]*se;
                const float r10 = U[4]*ce + U[6]*se, i10 = U[5]*ce + U[7]*se;
                const float r11 = U[6]*ce - U[4]*se, i11 = U[7]*ce - U[5]*se;
                U[0]=r00; U[1]=i00; U[2]=r01; U[3]=i01;
                U[4]=r10; U[5]=i10; U[6]=r11; U[7]=i11;
            }
        }
        f4 row0 = {U[0], U[1], U[2], U[3]};
        f4 row1 = {U[4], U[5], U[6], U[7]};
        sU[s_][q][0] = row0;
        sU[s_][q][1] = row1;
    }

    // ---- hoisted addresses (pass-invariant) ----
    int addrN[16];
    #pragma unroll
    for (int j = 0; j < 16; ++j) addrN[j] = physaddr((j << 8) | t);
    int waddr[4];
    {
        const int swz = ((t >> 2) & 7) << 2;
        #pragma unroll
        for (int k = 0; k < 4; ++k) waddr[k] = ((t << 4) | (k << 2)) ^ swz;
    }
    __syncthreads();

    // ---- 15 passes: 5 sweeps x 3 rot-4 passes; each pass = 4 in-register 2x2 gates
    //      (wires 4p..4p+3). CNOT chain (Gray-code perm) fused into the gather of
    //      pass 0 of sweeps 1..4. ----
    for (int sw = 0; sw < 5; ++sw) {
        #pragma unroll
        for (int p = 0; p < 3; ++p) {
            f2 aR[8], aI[8];
            if (p == 0 && sw > 0) {
                #pragma unroll
                for (int j = 0; j < 16; ++j) {
                    int v = (j << 8) | t;
                    v ^= (v >> 1);                  // new[v] = old[v ^ (v>>1)]
                    const int ph = physaddr(v);
                    const float re = sRe[ph], im = sIm[ph];
                    if (j & 1) { aR[j >> 1].y = re; aI[j >> 1].y = im; }
                    else       { aR[j >> 1].x = re; aI[j >> 1].x = im; }
                }
            } else {
                #pragma unroll
                for (int j = 0; j < 16; ++j) {
                    const float re = sRe[addrN[j]], im = sIm[addrN[j]];
                    if (j & 1) { aR[j >> 1].y = re; aI[j >> 1].y = im; }
                    else       { aR[j >> 1].x = re; aI[j >> 1].x = im; }
                }
            }

            // gate matrices for this pass (uniform LDS broadcast reads)
            float u0[8], u1[8], u2[8], u3[8];
            {
                const int wbase = 4 * p;
                #pragma unroll
                for (int g = 0; g < 4; ++g) {
                    const f4 r0 = sU[sw][wbase + g][0];
                    const f4 r1 = sU[sw][wbase + g][1];
                    float* ug = (g == 0) ? u0 : (g == 1) ? u1 : (g == 2) ? u2 : u3;
                    ug[0] = r0.x; ug[1] = r0.y; ug[2] = r0.z; ug[3] = r0.w;
                    ug[4] = r1.x; ug[5] = r1.y; ug[6] = r1.z; ug[7] = r1.w;
                }
            }

            // wire 4p+0: j-bit3 -> f2 pairs (i, i+4)
            #pragma unroll
            for (int i = 0; i < 4; ++i) gpair(aR[i], aI[i], aR[i + 4], aI[i + 4], u0);
            // wire 4p+1: j-bit2 -> (i, i+2)
            gpair(aR[0], aI[0], aR[2], aI[2], u1);
            gpair(aR[1], aI[1], aR[3], aI[3], u1);
            gpair(aR[4], aI[4], aR[6], aI[6], u1);
            gpair(aR[5], aI[5], aR[7], aI[7], u1);
            // wire 4p+2: j-bit1 -> (i, i+1)
            gpair(aR[0], aI[0], aR[1], aI[1], u2);
            gpair(aR[2], aI[2], aR[3], aI[3], u2);
            gpair(aR[4], aI[4], aR[5], aI[5], u2);
            gpair(aR[6], aI[6], aR[7], aI[7], u2);
            // wire 4p+3: j-bit0 -> within-f2
            #pragma unroll
            for (int i = 0; i < 8; ++i) gintra(aR[i], aI[i], u3);

            __syncthreads();   // all gathers complete before in-place scatter
            #pragma unroll
            for (int k = 0; k < 4; ++k) {
                f4 vr = {aR[2*k].x, aR[2*k].y, aR[2*k+1].x, aR[2*k+1].y};
                f4 vi = {aI[2*k].x, aI[2*k].y, aI[2*k+1].x, aI[2*k+1].y};
                *(f4*)(&sRe[waddr[k]]) = vr;
                *(f4*)(&sIm[waddr[k]]) = vi;
            }
            __syncthreads();
        }
    }

    // ---- measurement: standard layout; thread t owns i = t + 256k ----
    float zt = 0.f, z0 = 0.f, z1 = 0.f, z2 = 0.f, z3 = 0.f;
    #pragma unroll
    for (int k = 0; k < 16; ++k) {
        const int i = t + (k << 8);
        const int ph = physaddr(i);
        const float re = sRe[ph], im = sIm[ph];
        const float pv = fmaf(re, re, im * im);
        zt += pv;
        z0 += ((k >> 3) & 1) ? -pv : pv;   // wire 0 (bit 11)
        z1 += ((k >> 2) & 1) ? -pv : pv;   // wire 1
        z2 += ((k >> 1) & 1) ? -pv : pv;   // wire 2
        z3 += (k & 1)        ? -pv : pv;   // wire 3
    }
    float z[NQ];
    z[0] = z0; z[1] = z1; z[2] = z2; z[3] = z3;
    #pragma unroll
    for (int q = 4; q < NQ; ++q)
        z[q] = ((t >> (11 - q)) & 1) ? -zt : zt;

    #pragma unroll
    for (int q = 0; q < NQ; ++q) {
        float v = z[q];
        v += __shfl_xor(v, 1);  v += __shfl_xor(v, 2);
        v += __shfl_xor(v, 4);  v += __shfl_xor(v, 8);
        v += __shfl_xor(v, 16); v += __shfl_xor(v, 32);
        z[q] = v;
    }
    const int wv = t >> 6;
    if ((t & 63) == 0) {
        #pragma unroll
        for (int q = 0; q < NQ; ++q) sWred[wv][q] = z[q];
    }
    __syncthreads();
    if (t < NQ)
        out[(size_t)b * NQ + t] = sWred[0][t] + sWred[1][t] + sWred[2][t] + sWred[3][t];
}

extern "C" void kernel_launch(void* const* d_in, const int* in_sizes, int n_in,
                              void* d_out, int out_size, void* d_ws, size_t ws_size,
                              hipStream_t stream) {
    const float* x    = (const float*)d_in[0];
    const float* Wp   = (const float*)d_in[1];
    const float* bp   = (const float*)d_in[2];
    const float* w    = (const float*)d_in[3];
    const float* scal = (const float*)d_in[4];
    float* outp = (float*)d_out;
    hipLaunchKernelGGL(qsim_kernel, dim3(4096), dim3(256), 0, stream,
                       x, Wp, bp, w, scal, outp);
}